// Round 14
// baseline (359.618 us; speedup 1.0000x reference)
//
#include <hip/hip_runtime.h>
#include <hip/hip_bf16.h>

#define RREL 8
#define HEADS 4
#define DH 128          // hidden / out dim of both RGAT layers
#define CIN1 256        // layer-1 input dim (128 kg + 128 ccle-enc)
#define BN 144          // GEMM tile cols: 128 main + 8 aq/ak + 8 pad
#define CSP2 132        // epilogue LDS stride

typedef unsigned short ushortT;
typedef __attribute__((ext_vector_type(8))) short short8;
typedef __attribute__((ext_vector_type(4))) float f32x4;

__device__ __forceinline__ float lrelu(float x, float s) { return x > 0.f ? x : s * x; }

__device__ __forceinline__ float bf2f(unsigned short u) {
    return __uint_as_float(((unsigned)u) << 16);
}
__device__ __forceinline__ unsigned short f2bf(float f) {
    unsigned u = __float_as_uint(f);
    return (unsigned short)((u + 0x7fffu + ((u >> 16) & 1u)) >> 16);   // RNE
}

__device__ __forceinline__ void glds16(const ushortT* g, ushortT* l) {
    __builtin_amdgcn_global_load_lds(
        (const __attribute__((address_space(1))) unsigned int*)g,
        (__attribute__((address_space(3))) unsigned int*)l, 16, 0, 0);
}

// ---------------------------------------------------------------------------
// Encoder, two-phase: h[32] once per node (LDS), then per-(node,d) matvec with
// w2 columns held in registers. 64 nodes per block; kg copy fused.
__global__ __launch_bounds__(256)
void encoder_kernel(const float* __restrict__ kg, const float* __restrict__ ccle,
                    const int* __restrict__ node_id,
                    const float* __restrict__ w1, const float* __restrict__ b1,
                    const float* __restrict__ w2, const float* __restrict__ b2,
                    ushortT* __restrict__ xb, int N)
{
    __shared__ float w1s[4 * 32], b1s[32];
    __shared__ float hs[64][36];                 // padded row stride (16B-aligned)
    int tid = threadIdx.x;
    if (tid < 128) w1s[tid] = w1[tid];
    if (tid < 32) b1s[tid] = b1[tid];

    int d0 = tid & 63;
    int w = tid >> 6;
    float w2c0[32], w2c1[32];
    #pragma unroll 8
    for (int j = 0; j < 32; j++) {
        w2c0[j] = w2[j * 128 + d0];
        w2c1[j] = w2[j * 128 + d0 + 64];
    }
    float bb0 = b2[d0], bb1 = b2[d0 + 64];
    int chunk = blockIdx.x * 64;
    __syncthreads();

    {
        int ln = tid >> 2;
        int n = chunk + ln;
        if (n < N) {
            int nid = node_id[n];
            float c0 = ccle[nid * 4 + 0], c1 = ccle[nid * 4 + 1];
            float c2 = ccle[nid * 4 + 2], c3 = ccle[nid * 4 + 3];
            int jb = (tid & 3) * 8;
            #pragma unroll
            for (int jj = 0; jj < 8; jj++) {
                int j = jb + jj;
                float h = fmaf(c0, w1s[j], fmaf(c1, w1s[32 + j],
                          fmaf(c2, w1s[64 + j], fmaf(c3, w1s[96 + j], b1s[j]))));
                hs[ln][j] = lrelu(h, 0.01f);
            }
        }
    }
    __syncthreads();

    for (int it = 0; it < 16; it++) {
        int ln = it * 4 + w;
        int gn = chunk + ln;
        if (gn >= N) continue;
        int nid = node_id[gn];
        ushortT* xrow = xb + (long)gn * CIN1;
        xrow[d0]      = f2bf(kg[(long)nid * 128 + d0]);
        xrow[d0 + 64] = f2bf(kg[(long)nid * 128 + d0 + 64]);
        float o0 = bb0, o1 = bb1;
        const float4* hp = (const float4*)hs[ln];
        #pragma unroll
        for (int v = 0; v < 8; v++) {
            float4 hv = hp[v];
            o0 = fmaf(hv.x, w2c0[v * 4 + 0], o0);
            o1 = fmaf(hv.x, w2c1[v * 4 + 0], o1);
            o0 = fmaf(hv.y, w2c0[v * 4 + 1], o0);
            o1 = fmaf(hv.y, w2c1[v * 4 + 1], o1);
            o0 = fmaf(hv.z, w2c0[v * 4 + 2], o0);
            o1 = fmaf(hv.z, w2c1[v * 4 + 2], o1);
            o0 = fmaf(hv.w, w2c0[v * 4 + 3], o0);
            o1 = fmaf(hv.w, w2c1[v * 4 + 3], o1);
        }
        xrow[128 + d0]      = f2bf(o0);
        xrow[128 + d0 + 64] = f2bf(o1);
    }
}

// ---------------------------------------------------------------------------
// Build WT: 9 slots x [BN][K] bf16.
__global__ __launch_bounds__(256)
void wtrans_kernel(const float* __restrict__ W, const float* __restrict__ q,
                   const float* __restrict__ kv, const float* __restrict__ SW,
                   ushortT* __restrict__ WT, int K)
{
    long o = (long)blockIdx.x * 256 + threadIdx.x;
    long total = (long)9 * BN * K;
    if (o >= total) return;
    int k = (int)(o % K);
    long t = o / K;
    int d = (int)(t % BN);
    int r = (int)(t / BN);
    float v = 0.f;
    if (r < 8) {
        const float* Wr = W + ((long)r * K + k) * 128;
        if (d < 128) v = Wr[d];
        else if (d < 132) {
            int h = d - 128; float s = 0.f;
            for (int c = 0; c < 128; c++) s += Wr[c] * q[c * 4 + h];
            v = s;
        } else if (d < 136) {
            int h = d - 132; float s = 0.f;
            for (int c = 0; c < 128; c++) s += Wr[c] * kv[c * 4 + h];
            v = s;
        }
    } else if (d < 128) {
        v = SW[(long)k * 128 + d];
    }
    WT[o] = f2bf(v);
}

// ---------------------------------------------------------------------------
// bf16 MFMA GEMM, 128xBN tile, 8 waves (512 thr) x 16 rows each -> acc[9]
// (36 VGPR acc vs 72) so unified regfile allows ~6 waves/SIMD occupancy.
// BK=64, global_load_lds staging with XOR slot-swizzle; XCD-chunked swizzle.
// z (=bid%9) 0..7: write hr[r] + aqk (cols 128..135); z=8: skip (bf16 out).
__global__ __launch_bounds__(512, 6)
void mfma_gemm(const ushortT* __restrict__ A, const ushortT* __restrict__ Askip,
               const ushortT* __restrict__ WT, ushortT* __restrict__ hrC,
               float* __restrict__ aqkout, const float* __restrict__ bskip,
               ushortT* __restrict__ skipout, int actskip,
               int M, int K)
{
    __shared__ ushortT smem[128 * 64 + BN * 64];   // As | Bs ; reused as Cs
    ushortT* As = smem;
    ushortT* Bs = smem + 128 * 64;
    int tid = threadIdx.x;
    int lane = tid & 63, w = tid >> 6;             // 8 waves
    int l15 = lane & 15, lhi = lane >> 4;

    // bijective XCD-chunked swizzle (m204)
    int nwg = gridDim.x;
    int orig = blockIdx.x;
    int qq = nwg >> 3, rrem = nwg & 7;
    int xcd = orig & 7, o8 = orig >> 3;
    int bid = (xcd < rrem ? xcd * (qq + 1) : rrem * (qq + 1) + (xcd - rrem) * qq) + o8;

    int r = bid % 9;
    int m0 = (bid / 9) * 128;
    const ushortT* Ab = (r < 8) ? A : Askip;
    const ushortT* Wb = WT + (long)r * BN * K;
    int wbase = (tid >> 6) << 6;                   // wave-uniform lane-0 tid
    f32x4 acc[9] = {};

    for (int k0 = 0; k0 < K; k0 += 64) {
        #pragma unroll
        for (int it = 0; it < 2; it++) {           // A: 128 rows x 8 slots
            int idx = it * 512 + tid;
            int row = idx >> 3;
            int ko = ((idx ^ (idx >> 3)) & 7) * 8; // inverse-swizzled source slot
            glds16(Ab + (long)(m0 + row) * K + k0 + ko,
                   As + (it * 512 + wbase) * 8);
        }
        #pragma unroll
        for (int it = 0; it < 2; it++) {           // B rows 0..127
            int idx = it * 512 + tid;
            int row = idx >> 3;
            int ko = ((idx ^ (idx >> 3)) & 7) * 8;
            glds16(Wb + (long)row * K + k0 + ko,
                   Bs + (it * 512 + wbase) * 8);
        }
        if (tid < 128) {                           // B rows 128..143 (waves 0,1)
            int idx = 1024 + tid;
            int row = idx >> 3;
            int ko = ((idx ^ (idx >> 3)) & 7) * 8;
            glds16(Wb + (long)row * K + k0 + ko,
                   Bs + (1024 + wbase) * 8);
        }
        __syncthreads();
        #pragma unroll
        for (int kk = 0; kk < 64; kk += 32) {
            int xoro = ((((kk >> 3) + lhi) ^ (l15 & 7)) << 3);  // swizzled read slot
            short8 af0 = *(const short8*)(As + (w * 16 + l15) * 64 + xoro);
            #pragma unroll
            for (int j = 0; j < 9; j++) {
                short8 bf8 = *(const short8*)(Bs + (j * 16 + l15) * 64 + xoro);
                acc[j] = __builtin_amdgcn_mfma_f32_16x16x32_bf16(af0, bf8, acc[j], 0, 0, 0);
            }
        }
        __syncthreads();
    }

    // aqk direct from acc fragment j=8 (cols 128..135), layout [r][n][8]
    if (r < 8 && l15 < 8) {
        #pragma unroll
        for (int g = 0; g < 4; g++) {
            int row = w * 16 + lhi * 4 + g;
            if (m0 + row < M)
                aqkout[((long)r * M + m0 + row) * 8 + l15] = acc[8][g];
        }
    }

    // main 128 cols: stage to LDS (coalesce), then global write
    ushortT* Cs = smem;                            // [128][CSP2]
    #pragma unroll
    for (int j = 0; j < 8; j++) {
        int row = w * 16 + lhi * 4;
        int col = j * 16 + l15;
        #pragma unroll
        for (int g = 0; g < 4; g++)
            Cs[(row + g) * CSP2 + col] = f2bf(acc[j][g]);
    }
    __syncthreads();
    #pragma unroll
    for (int it = 0; it < 4; it++) {
        int idx = it * 4096 + tid * 8;
        int row = idx >> 7, col = idx & 127;
        if (m0 + row >= M) continue;
        const ushortT* cp = Cs + row * CSP2 + col;
        if (r < 8) {
            long gofs = ((long)r * M + m0 + row) * DH + col;
            *(uint4*)(hrC + gofs) = *(const uint4*)cp;
        } else {
            float v[8];
            #pragma unroll
            for (int u = 0; u < 8; u++) {
                float x = bf2f(cp[u]) + bskip[col + u];
                if (actskip) x = lrelu(x, 0.01f);
                v[u] = x;
            }
            uint4 pk;
            pk.x = (unsigned)f2bf(v[0]) | ((unsigned)f2bf(v[1]) << 16);
            pk.y = (unsigned)f2bf(v[2]) | ((unsigned)f2bf(v[3]) << 16);
            pk.z = (unsigned)f2bf(v[4]) | ((unsigned)f2bf(v[5]) << 16);
            pk.w = (unsigned)f2bf(v[6]) | ((unsigned)f2bf(v[7]) << 16);
            *(uint4*)(skipout + (long)(m0 + row) * DH + col) = pk;
        }
    }
}

// ---------------------------------------------------------------------------
// CSR build: histogram -> exclusive scan -> scatter (sorted by dst)
// ILP-4: each thread handles 4 consecutive edges with independent atomics.
__global__ __launch_bounds__(256)
void hist_kernel(const int* __restrict__ dst, int* __restrict__ deg, int E)
{
    int e0 = (blockIdx.x * 256 + threadIdx.x) * 4;
    if (e0 + 3 < E) {
        int4 d4 = *(const int4*)(dst + e0);
        atomicAdd(&deg[d4.x], 1);
        atomicAdd(&deg[d4.y], 1);
        atomicAdd(&deg[d4.z], 1);
        atomicAdd(&deg[d4.w], 1);
    } else {
        for (int e = e0; e < E; e++) atomicAdd(&deg[dst[e]], 1);
    }
}

#define SCAN_BLK 1024
__global__ __launch_bounds__(256)
void scan1_kernel(const int* __restrict__ deg, int* __restrict__ excl,
                  int* __restrict__ bsum, int n)
{
    __shared__ int ts[256];
    int b0 = blockIdx.x * SCAN_BLK;
    int tid = threadIdx.x;
    int v[4]; int s = 0;
    #pragma unroll
    for (int i = 0; i < 4; i++) {
        int idx = b0 + tid * 4 + i;
        v[i] = (idx < n) ? deg[idx] : 0;
        s += v[i];
    }
    ts[tid] = s;
    __syncthreads();
    for (int off = 1; off < 256; off <<= 1) {
        int t = (tid >= off) ? ts[tid - off] : 0;
        __syncthreads();
        ts[tid] += t;
        __syncthreads();
    }
    int ex = ts[tid] - s;
    #pragma unroll
    for (int i = 0; i < 4; i++) {
        int idx = b0 + tid * 4 + i;
        if (idx < n) excl[idx] = ex;
        ex += v[i];
    }
    if (tid == 255) bsum[blockIdx.x] = ts[255];
}

__global__ void scan2_kernel(int* __restrict__ bsum, int nb)
{
    if (threadIdx.x == 0 && blockIdx.x == 0) {
        int a = 0;
        for (int i = 0; i < nb; i++) { int t = bsum[i]; bsum[i] = a; a += t; }
    }
}

__global__ __launch_bounds__(256)
void scan3_kernel(int* __restrict__ rowptr, const int* __restrict__ bsum,
                  int* __restrict__ cursor, int n, int E)
{
    int idx = blockIdx.x * 256 + threadIdx.x;
    if (idx < n) {
        int v = rowptr[idx] + bsum[idx / SCAN_BLK];
        rowptr[idx] = v;
        cursor[idx] = v;
    }
    if (idx == 0) rowptr[n] = E;
}

// scatter packed (et<<17)|src — ILP-4, 4 independent atomic round-trips/thread
__global__ __launch_bounds__(256)
void scatter_kernel(const int* __restrict__ src, const int* __restrict__ dst,
                    const int* __restrict__ et, int* __restrict__ cursor,
                    int* __restrict__ ses, int E)
{
    int e0 = (blockIdx.x * 256 + threadIdx.x) * 4;
    if (e0 + 3 < E) {
        int4 s4 = *(const int4*)(src + e0);
        int4 d4 = *(const int4*)(dst + e0);
        int4 t4 = *(const int4*)(et + e0);
        int p0 = atomicAdd(&cursor[d4.x], 1);
        int p1 = atomicAdd(&cursor[d4.y], 1);
        int p2 = atomicAdd(&cursor[d4.z], 1);
        int p3 = atomicAdd(&cursor[d4.w], 1);
        ses[p0] = (t4.x << 17) | s4.x;
        ses[p1] = (t4.y << 17) | s4.y;
        ses[p2] = (t4.z << 17) | s4.z;
        ses[p3] = (t4.w << 17) | s4.w;
    } else {
        for (int e = e0; e < E; e++) {
            int pos = atomicAdd(&cursor[dst[e]], 1);
            ses[pos] = (et[e] << 17) | src[e];
        }
    }
}

// ---------------------------------------------------------------------------
// Fused segment softmax + aggregation (round-7 structure, packed edge meta,
// aqk [r][n][8] layout). One wave per dst node. ADDS reads bf16 skip.
template<typename CT, bool ADDS>
__global__ __launch_bounds__(256)
void fused_agg(const int* __restrict__ rowptr, const int* __restrict__ ses,
               const float* __restrict__ aqk, const ushortT* __restrict__ hr,
               const float* __restrict__ bias, const ushortT* __restrict__ adds,
               void* __restrict__ outp, int N, int act)
{
    __shared__ ushortT hrb[4][16][128];
    __shared__ float pbuf[4][16][4];
    int w = threadIdx.x >> 6, lane = threadIdx.x & 63;
    int d = blockIdx.x * 4 + w;
    if (d >= N) return;
    int beg = rowptr[d], end = rowptr[d + 1];
    int el = lane & 15, hq = lane >> 4;
    float m = -1e30f, den = 0.f, o0 = 0.f, o1 = 0.f;

    for (int base = beg; base < end; base += 16) {
        int nchunk = end - base; if (nchunk > 16) nchunk = 16;
        int pk = 0;
        float a = -1e30f;
        if (el < nchunk) {
            pk = ses[base + el];
            int s = pk & 0x1FFFF, t = pk >> 17;
            a = lrelu(aqk[((long)t * N + d) * 8 + hq]
                    + aqk[((long)t * N + s) * 8 + 4 + hq], 0.2f);
        }
        float v = a;
        v = fmaxf(v, __shfl_xor(v, 1));
        v = fmaxf(v, __shfl_xor(v, 2));
        v = fmaxf(v, __shfl_xor(v, 4));
        v = fmaxf(v, __shfl_xor(v, 8));
        float mn = fmaxf(m, v);
        float scale = __expf(m - mn);
        m = mn;
        float p = (el < nchunk) ? __expf(a - mn) : 0.f;
        pbuf[w][el][hq] = p;
        float ps = p;
        ps += __shfl_xor(ps, 1);
        ps += __shfl_xor(ps, 2);
        ps += __shfl_xor(ps, 4);
        ps += __shfl_xor(ps, 8);
        den = den * scale + ps;
        // stage the chunk's hr rows: 4 passes x (4 rows x 16 lanes x 16B)
        #pragma unroll
        for (int pass = 0; pass < 4; pass++) {
            int rj = pass * 4 + (lane >> 4);
            int pj = __shfl(pk, rj);
            int sj = pj & 0x1FFFF, tj = pj >> 17;
            if (rj < nchunk) {
                uint4 hv = *(const uint4*)(hr + ((long)tj * N + sj) * DH + (lane & 15) * 8);
                *(uint4*)&hrb[w][rj][(lane & 15) * 8] = hv;
            }
        }
        o0 *= scale; o1 *= scale;
        asm volatile("s_waitcnt lgkmcnt(0)" ::: "memory");
        for (int j = 0; j < nchunk; j++) {
            float pj = pbuf[w][j][hq];
            unsigned hv = *(const unsigned*)&hrb[w][j][lane * 2];
            o0 = fmaf(pj, bf2f((ushortT)hv), o0);
            o1 = fmaf(pj, bf2f((ushortT)(hv >> 16)), o1);
        }
    }
    float inv = (den > 0.f) ? 1.f / den : 0.f;
    o0 *= inv; o1 *= inv;
    if (bias) { o0 += bias[2 * lane]; o1 += bias[2 * lane + 1]; }
    if constexpr (ADDS) {
        unsigned sv = ((const unsigned*)adds)[(long)d * 64 + lane];
        o0 += bf2f((ushortT)sv);
        o1 += bf2f((ushortT)(sv >> 16));
    }
    if (act) { o0 = lrelu(o0, 0.01f); o1 = lrelu(o1, 0.01f); }
    if constexpr (sizeof(CT) == 2) {
        unsigned pk2 = (unsigned)f2bf(o0) | ((unsigned)f2bf(o1) << 16);
        ((unsigned*)outp)[(long)d * 64 + lane] = pk2;
    } else {
        *(float2*)((float*)outp + (long)d * DH + lane * 2) = make_float2(o0, o1);
    }
}

__global__ __launch_bounds__(256)
void fill_report(float* __restrict__ out, float v, long total)
{
    long i = (long)blockIdx.x * 256 + threadIdx.x;
    if (i < total) out[i] = v;
}

// ---------------------------------------------------------------------------
extern "C" void kernel_launch(void* const* d_in, const int* in_sizes, int n_in,
                              void* d_out, int out_size, void* d_ws, size_t ws_size,
                              hipStream_t stream)
{
    const float* kg      = (const float*)d_in[0];
    const float* ccle    = (const float*)d_in[1];
    const int*   node_id = (const int*)d_in[2];
    const int*   eidx    = (const int*)d_in[3];
    const int*   etype   = (const int*)d_in[4];
    const float* cw1 = (const float*)d_in[5];
    const float* cb1 = (const float*)d_in[6];
    const float* cw2 = (const float*)d_in[7];
    const float* cb2 = (const float*)d_in[8];
    const float* W1  = (const float*)d_in[9];
    const float* q1  = (const float*)d_in[10];
    const float* k1  = (const float*)d_in[11];
    const float* b1  = (const float*)d_in[12];
    const float* W2  = (const float*)d_in[13];
    const float* q2  = (const float*)d_in[14];
    const float* k2  = (const float*)d_in[15];
    const float* b2  = (const float*)d_in[16];
    const float* sw1 = (const float*)d_in[17];
    const float* sb1 = (const float*)d_in[18];
    const float* sw2 = (const float*)d_in[19];
    const float* sb2 = (const float*)d_in[20];

    const int N = in_sizes[2];
    const int E = in_sizes[4];
    const int* src = eidx;
    const int* dst = eidx + E;

    dim3 blk(256);
    dim3 blk512(512);
    long nd = (long)N * 128;
    int nd_blocks = (int)((nd + 255) / 256);
    int eb4 = (E / 4 + 255) / 256;                 // ILP-4 edge kernels

    // ---- workspace layout ----
    const long WTN = (long)9 * BN * 256;           // WT slots (max K=256)
    size_t need = (size_t)N * (256 + 128 + 128 + 1024) * 2 + (size_t)WTN * 2
                + (size_t)N * 64 * 4 + (size_t)N * 128 * 4
                + ((size_t)3 * N + 257 + (size_t)E) * 4;
    if (ws_size < need) {
        fill_report<<<nd_blocks, blk, 0, stream>>>((float*)d_out,
            (float)(double)(ws_size >> 20), nd);
        return;
    }
    ushortT* xb  = (ushortT*)d_ws;                 // 256N
    ushortT* x1b = xb + (long)N * CIN1;            // 128N
    ushortT* s1b = x1b + (long)N * DH;             // 128N
    ushortT* hr  = s1b + (long)N * DH;             // 1024N
    ushortT* WT  = hr + (long)RREL * N * DH;       // WTN
    float* aqk   = (float*)(WT + WTN);             // 64N, layout [r][n][8]
    ushortT* s2b = (ushortT*)(aqk + (long)N * 64); // 128N bf16 (region is 128N f32)
    int* rowptr  = (int*)((float*)s2b + (long)N * DH);  // N+1
    int* cursor  = rowptr + (N + 1);
    int* deg     = cursor + N;
    int* bsum    = deg + N;
    int* ses     = bsum + 256;                     // E packed (et<<17)|src

    int nb = (N + SCAN_BLK - 1) / SCAN_BLK;
    int fgrid = (N + 3) / 4;
    int mblocks = (N + 127) / 128;
    dim3 ggrid(mblocks * 9);

    // encoder -> xb (bf16 [kg | enc]); 64 nodes per block
    encoder_kernel<<<(N + 63) / 64, blk, 0, stream>>>(kg, ccle, node_id,
        cw1, cb1, cw2, cb2, xb, N);

    // CSR build (shared by both layers)
    hipMemsetAsync(deg, 0, (size_t)N * sizeof(int), stream);
    hist_kernel<<<eb4, blk, 0, stream>>>(dst, deg, E);
    scan1_kernel<<<nb, blk, 0, stream>>>(deg, rowptr, bsum, N);
    scan2_kernel<<<1, 64, 0, stream>>>(bsum, nb);
    scan3_kernel<<<(N + 255) / 256, blk, 0, stream>>>(rowptr, bsum, cursor, N, E);
    scatter_kernel<<<eb4, blk, 0, stream>>>(src, dst, etype, cursor, ses, E);

    // ---- layer 1 ----
    wtrans_kernel<<<(int)(((long)9 * BN * CIN1 + 255) / 256), blk, 0, stream>>>(
        W1, q1, k1, sw1, WT, CIN1);
    mfma_gemm<<<ggrid, blk512, 0, stream>>>(xb, xb, WT, hr, aqk, sb1, s1b,
        /*actskip=*/1, N, CIN1);
    fused_agg<ushortT, false><<<fgrid, blk, 0, stream>>>(rowptr, ses,
        aqk, hr, b1, nullptr, x1b, N, 1);

    // ---- layer 2 ----
    wtrans_kernel<<<(int)(((long)9 * BN * DH + 255) / 256), blk, 0, stream>>>(
        W2, q2, k2, sw2, WT, DH);
    mfma_gemm<<<ggrid, blk512, 0, stream>>>(x1b, s1b, WT, hr, aqk, sb2, s2b,
        /*actskip=*/0, N, DH);
    fused_agg<float, true><<<fgrid, blk, 0, stream>>>(rowptr, ses,
        aqk, hr, b2, s2b, (float*)d_out, N, 1);
}

// Round 15
// 351.863 us; speedup vs baseline: 1.0220x; 1.0220x over previous
//
#include <hip/hip_runtime.h>
#include <hip/hip_bf16.h>

#define RREL 8
#define HEADS 4
#define DH 128          // hidden / out dim of both RGAT layers
#define CIN1 256        // layer-1 input dim (128 kg + 128 ccle-enc)
#define BN 144          // GEMM tile cols: 128 main + 8 aq/ak + 8 pad
#define CSP2 132        // epilogue LDS stride

typedef unsigned short ushortT;
typedef __attribute__((ext_vector_type(8))) short short8;
typedef __attribute__((ext_vector_type(4))) float f32x4;

__device__ __forceinline__ float lrelu(float x, float s) { return x > 0.f ? x : s * x; }

__device__ __forceinline__ float bf2f(unsigned short u) {
    return __uint_as_float(((unsigned)u) << 16);
}
__device__ __forceinline__ unsigned short f2bf(float f) {
    unsigned u = __float_as_uint(f);
    return (unsigned short)((u + 0x7fffu + ((u >> 16) & 1u)) >> 16);   // RNE
}

__device__ __forceinline__ void glds16(const ushortT* g, ushortT* l) {
    __builtin_amdgcn_global_load_lds(
        (const __attribute__((address_space(1))) unsigned int*)g,
        (__attribute__((address_space(3))) unsigned int*)l, 16, 0, 0);
}

// ---------------------------------------------------------------------------
// Encoder, two-phase: h[32] once per node (LDS), then per-(node,d) matvec with
// w2 columns held in registers. 64 nodes per block; kg copy fused.
__global__ __launch_bounds__(256)
void encoder_kernel(const float* __restrict__ kg, const float* __restrict__ ccle,
                    const int* __restrict__ node_id,
                    const float* __restrict__ w1, const float* __restrict__ b1,
                    const float* __restrict__ w2, const float* __restrict__ b2,
                    ushortT* __restrict__ xb, int N)
{
    __shared__ float w1s[4 * 32], b1s[32];
    __shared__ float hs[64][36];                 // padded row stride (16B-aligned)
    int tid = threadIdx.x;
    if (tid < 128) w1s[tid] = w1[tid];
    if (tid < 32) b1s[tid] = b1[tid];

    int d0 = tid & 63;
    int w = tid >> 6;
    float w2c0[32], w2c1[32];
    #pragma unroll 8
    for (int j = 0; j < 32; j++) {
        w2c0[j] = w2[j * 128 + d0];
        w2c1[j] = w2[j * 128 + d0 + 64];
    }
    float bb0 = b2[d0], bb1 = b2[d0 + 64];
    int chunk = blockIdx.x * 64;
    __syncthreads();

    {
        int ln = tid >> 2;
        int n = chunk + ln;
        if (n < N) {
            int nid = node_id[n];
            float c0 = ccle[nid * 4 + 0], c1 = ccle[nid * 4 + 1];
            float c2 = ccle[nid * 4 + 2], c3 = ccle[nid * 4 + 3];
            int jb = (tid & 3) * 8;
            #pragma unroll
            for (int jj = 0; jj < 8; jj++) {
                int j = jb + jj;
                float h = fmaf(c0, w1s[j], fmaf(c1, w1s[32 + j],
                          fmaf(c2, w1s[64 + j], fmaf(c3, w1s[96 + j], b1s[j]))));
                hs[ln][j] = lrelu(h, 0.01f);
            }
        }
    }
    __syncthreads();

    for (int it = 0; it < 16; it++) {
        int ln = it * 4 + w;
        int gn = chunk + ln;
        if (gn >= N) continue;
        int nid = node_id[gn];
        ushortT* xrow = xb + (long)gn * CIN1;
        xrow[d0]      = f2bf(kg[(long)nid * 128 + d0]);
        xrow[d0 + 64] = f2bf(kg[(long)nid * 128 + d0 + 64]);
        float o0 = bb0, o1 = bb1;
        const float4* hp = (const float4*)hs[ln];
        #pragma unroll
        for (int v = 0; v < 8; v++) {
            float4 hv = hp[v];
            o0 = fmaf(hv.x, w2c0[v * 4 + 0], o0);
            o1 = fmaf(hv.x, w2c1[v * 4 + 0], o1);
            o0 = fmaf(hv.y, w2c0[v * 4 + 1], o0);
            o1 = fmaf(hv.y, w2c1[v * 4 + 1], o1);
            o0 = fmaf(hv.z, w2c0[v * 4 + 2], o0);
            o1 = fmaf(hv.z, w2c1[v * 4 + 2], o1);
            o0 = fmaf(hv.w, w2c0[v * 4 + 3], o0);
            o1 = fmaf(hv.w, w2c1[v * 4 + 3], o1);
        }
        xrow[128 + d0]      = f2bf(o0);
        xrow[128 + d0 + 64] = f2bf(o1);
    }
}

// ---------------------------------------------------------------------------
// Build WT: 9 slots x [BN][K] bf16.
__global__ __launch_bounds__(256)
void wtrans_kernel(const float* __restrict__ W, const float* __restrict__ q,
                   const float* __restrict__ kv, const float* __restrict__ SW,
                   ushortT* __restrict__ WT, int K)
{
    long o = (long)blockIdx.x * 256 + threadIdx.x;
    long total = (long)9 * BN * K;
    if (o >= total) return;
    int k = (int)(o % K);
    long t = o / K;
    int d = (int)(t % BN);
    int r = (int)(t / BN);
    float v = 0.f;
    if (r < 8) {
        const float* Wr = W + ((long)r * K + k) * 128;
        if (d < 128) v = Wr[d];
        else if (d < 132) {
            int h = d - 128; float s = 0.f;
            for (int c = 0; c < 128; c++) s += Wr[c] * q[c * 4 + h];
            v = s;
        } else if (d < 136) {
            int h = d - 132; float s = 0.f;
            for (int c = 0; c < 128; c++) s += Wr[c] * kv[c * 4 + h];
            v = s;
        }
    } else if (d < 128) {
        v = SW[(long)k * 128 + d];
    }
    WT[o] = f2bf(v);
}

// ---------------------------------------------------------------------------
// bf16 MFMA GEMM, 128xBN tile (round-11 geometry), BK=64, global_load_lds
// staging with XOR slot-swizzle; XCD-chunked block swizzle.
// z (=bid%9) 0..7: write hr[r] + aqk (cols 128..135); z=8: skip (bf16 out).
__global__ __launch_bounds__(256, 4)
void mfma_gemm(const ushortT* __restrict__ A, const ushortT* __restrict__ Askip,
               const ushortT* __restrict__ WT, ushortT* __restrict__ hrC,
               float* __restrict__ aqkout, const float* __restrict__ bskip,
               ushortT* __restrict__ skipout, int actskip,
               int M, int K)
{
    __shared__ ushortT smem[128 * 64 + BN * 64];   // As | Bs ; reused as Cs
    ushortT* As = smem;
    ushortT* Bs = smem + 128 * 64;
    int tid = threadIdx.x;
    int lane = tid & 63, w = tid >> 6;
    int l15 = lane & 15, lhi = lane >> 4;

    // bijective XCD-chunked swizzle (m204)
    int nwg = gridDim.x;
    int orig = blockIdx.x;
    int qq = nwg >> 3, rrem = nwg & 7;
    int xcd = orig & 7, o8 = orig >> 3;
    int bid = (xcd < rrem ? xcd * (qq + 1) : rrem * (qq + 1) + (xcd - rrem) * qq) + o8;

    int r = bid % 9;
    int m0 = (bid / 9) * 128;
    const ushortT* Ab = (r < 8) ? A : Askip;
    const ushortT* Wb = WT + (long)r * BN * K;
    int wbase = (tid >> 6) << 6;                   // wave-uniform lane-0 tid
    f32x4 acc[2][9] = {};

    for (int k0 = 0; k0 < K; k0 += 64) {
        #pragma unroll
        for (int it = 0; it < 4; it++) {
            int idx = it * 256 + tid;
            int row = idx >> 3;
            int ko = ((idx ^ (idx >> 3)) & 7) * 8;     // inverse-swizzled source slot
            glds16(Ab + (long)(m0 + row) * K + k0 + ko,
                   As + (it * 256 + wbase) * 8);
        }
        #pragma unroll
        for (int it = 0; it < 4; it++) {
            int idx = it * 256 + tid;
            int row = idx >> 3;
            int ko = ((idx ^ (idx >> 3)) & 7) * 8;
            glds16(Wb + (long)row * K + k0 + ko,
                   Bs + (it * 256 + wbase) * 8);
        }
        if (tid < 128) {                               // B rows 128..143
            int idx = 1024 + tid;
            int row = idx >> 3;
            int ko = ((idx ^ (idx >> 3)) & 7) * 8;
            glds16(Wb + (long)row * K + k0 + ko,
                   Bs + (1024 + wbase) * 8);
        }
        __syncthreads();
        #pragma unroll
        for (int kk = 0; kk < 64; kk += 32) {
            int xoro = ((((kk >> 3) + lhi) ^ (l15 & 7)) << 3);  // swizzled read slot
            short8 af0 = *(const short8*)(As + (w * 32 + l15) * 64 + xoro);
            short8 af1 = *(const short8*)(As + (w * 32 + 16 + l15) * 64 + xoro);
            #pragma unroll
            for (int j = 0; j < 9; j++) {
                short8 bf8 = *(const short8*)(Bs + (j * 16 + l15) * 64 + xoro);
                acc[0][j] = __builtin_amdgcn_mfma_f32_16x16x32_bf16(af0, bf8, acc[0][j], 0, 0, 0);
                acc[1][j] = __builtin_amdgcn_mfma_f32_16x16x32_bf16(af1, bf8, acc[1][j], 0, 0, 0);
            }
        }
        __syncthreads();
    }

    // aqk direct from acc fragment j=8 (cols 128..135), layout [r][n][8]
    if (r < 8 && l15 < 8) {
        #pragma unroll
        for (int i = 0; i < 2; i++)
            #pragma unroll
            for (int g = 0; g < 4; g++) {
                int row = w * 32 + i * 16 + lhi * 4 + g;
                if (m0 + row < M)
                    aqkout[((long)r * M + m0 + row) * 8 + l15] = acc[i][8][g];
            }
    }

    // main 128 cols: stage to LDS (coalesce), then global write
    ushortT* Cs = smem;                            // [128][CSP2]
    #pragma unroll
    for (int i = 0; i < 2; i++)
        #pragma unroll
        for (int j = 0; j < 8; j++) {
            int row = w * 32 + i * 16 + lhi * 4;
            int col = j * 16 + l15;
            #pragma unroll
            for (int g = 0; g < 4; g++)
                Cs[(row + g) * CSP2 + col] = f2bf(acc[i][j][g]);
        }
    __syncthreads();
    #pragma unroll
    for (int it = 0; it < 8; it++) {
        int idx = it * 2048 + tid * 8;
        int row = idx >> 7, col = idx & 127;
        if (m0 + row >= M) continue;
        const ushortT* cp = Cs + row * CSP2 + col;
        if (r < 8) {
            long gofs = ((long)r * M + m0 + row) * DH + col;
            *(uint4*)(hrC + gofs) = *(const uint4*)cp;
        } else {
            float v[8];
            #pragma unroll
            for (int u = 0; u < 8; u++) {
                float x = bf2f(cp[u]) + bskip[col + u];
                if (actskip) x = lrelu(x, 0.01f);
                v[u] = x;
            }
            uint4 pk;
            pk.x = (unsigned)f2bf(v[0]) | ((unsigned)f2bf(v[1]) << 16);
            pk.y = (unsigned)f2bf(v[2]) | ((unsigned)f2bf(v[3]) << 16);
            pk.z = (unsigned)f2bf(v[4]) | ((unsigned)f2bf(v[5]) << 16);
            pk.w = (unsigned)f2bf(v[6]) | ((unsigned)f2bf(v[7]) << 16);
            *(uint4*)(skipout + (long)(m0 + row) * DH + col) = pk;
        }
    }
}

// ---------------------------------------------------------------------------
// CSR build: histogram -> exclusive scan -> scatter (sorted by dst)
// ILP-4: each thread handles 4 consecutive edges with independent atomics.
__global__ __launch_bounds__(256)
void hist_kernel(const int* __restrict__ dst, int* __restrict__ deg, int E)
{
    int e0 = (blockIdx.x * 256 + threadIdx.x) * 4;
    if (e0 + 3 < E) {
        int4 d4 = *(const int4*)(dst + e0);
        atomicAdd(&deg[d4.x], 1);
        atomicAdd(&deg[d4.y], 1);
        atomicAdd(&deg[d4.z], 1);
        atomicAdd(&deg[d4.w], 1);
    } else {
        for (int e = e0; e < E; e++) atomicAdd(&deg[dst[e]], 1);
    }
}

#define SCAN_BLK 1024
__global__ __launch_bounds__(256)
void scan1_kernel(const int* __restrict__ deg, int* __restrict__ excl,
                  int* __restrict__ bsum, int n)
{
    __shared__ int ts[256];
    int b0 = blockIdx.x * SCAN_BLK;
    int tid = threadIdx.x;
    int v[4]; int s = 0;
    #pragma unroll
    for (int i = 0; i < 4; i++) {
        int idx = b0 + tid * 4 + i;
        v[i] = (idx < n) ? deg[idx] : 0;
        s += v[i];
    }
    ts[tid] = s;
    __syncthreads();
    for (int off = 1; off < 256; off <<= 1) {
        int t = (tid >= off) ? ts[tid - off] : 0;
        __syncthreads();
        ts[tid] += t;
        __syncthreads();
    }
    int ex = ts[tid] - s;
    #pragma unroll
    for (int i = 0; i < 4; i++) {
        int idx = b0 + tid * 4 + i;
        if (idx < n) excl[idx] = ex;
        ex += v[i];
    }
    if (tid == 255) bsum[blockIdx.x] = ts[255];
}

__global__ void scan2_kernel(int* __restrict__ bsum, int nb)
{
    if (threadIdx.x == 0 && blockIdx.x == 0) {
        int a = 0;
        for (int i = 0; i < nb; i++) { int t = bsum[i]; bsum[i] = a; a += t; }
    }
}

__global__ __launch_bounds__(256)
void scan3_kernel(int* __restrict__ rowptr, const int* __restrict__ bsum,
                  int* __restrict__ cursor, int n, int E)
{
    int idx = blockIdx.x * 256 + threadIdx.x;
    if (idx < n) {
        int v = rowptr[idx] + bsum[idx / SCAN_BLK];
        rowptr[idx] = v;
        cursor[idx] = v;
    }
    if (idx == 0) rowptr[n] = E;
}

// scatter packed (et<<17)|src — ILP-4, 4 independent atomic round-trips/thread
__global__ __launch_bounds__(256)
void scatter_kernel(const int* __restrict__ src, const int* __restrict__ dst,
                    const int* __restrict__ et, int* __restrict__ cursor,
                    int* __restrict__ ses, int E)
{
    int e0 = (blockIdx.x * 256 + threadIdx.x) * 4;
    if (e0 + 3 < E) {
        int4 s4 = *(const int4*)(src + e0);
        int4 d4 = *(const int4*)(dst + e0);
        int4 t4 = *(const int4*)(et + e0);
        int p0 = atomicAdd(&cursor[d4.x], 1);
        int p1 = atomicAdd(&cursor[d4.y], 1);
        int p2 = atomicAdd(&cursor[d4.z], 1);
        int p3 = atomicAdd(&cursor[d4.w], 1);
        ses[p0] = (t4.x << 17) | s4.x;
        ses[p1] = (t4.y << 17) | s4.y;
        ses[p2] = (t4.z << 17) | s4.z;
        ses[p3] = (t4.w << 17) | s4.w;
    } else {
        for (int e = e0; e < E; e++) {
            int pos = atomicAdd(&cursor[dst[e]], 1);
            ses[pos] = (et[e] << 17) | src[e];
        }
    }
}

// ---------------------------------------------------------------------------
// Fused segment softmax + aggregation (round-7 structure, packed edge meta,
// aqk [r][n][8] layout). One wave per dst node. ADDS reads bf16 skip.
template<typename CT, bool ADDS>
__global__ __launch_bounds__(256)
void fused_agg(const int* __restrict__ rowptr, const int* __restrict__ ses,
               const float* __restrict__ aqk, const ushortT* __restrict__ hr,
               const float* __restrict__ bias, const ushortT* __restrict__ adds,
               void* __restrict__ outp, int N, int act)
{
    __shared__ ushortT hrb[4][16][128];
    __shared__ float pbuf[4][16][4];
    int w = threadIdx.x >> 6, lane = threadIdx.x & 63;
    int d = blockIdx.x * 4 + w;
    if (d >= N) return;
    int beg = rowptr[d], end = rowptr[d + 1];
    int el = lane & 15, hq = lane >> 4;
    float m = -1e30f, den = 0.f, o0 = 0.f, o1 = 0.f;

    for (int base = beg; base < end; base += 16) {
        int nchunk = end - base; if (nchunk > 16) nchunk = 16;
        int pk = 0;
        float a = -1e30f;
        if (el < nchunk) {
            pk = ses[base + el];
            int s = pk & 0x1FFFF, t = pk >> 17;
            a = lrelu(aqk[((long)t * N + d) * 8 + hq]
                    + aqk[((long)t * N + s) * 8 + 4 + hq], 0.2f);
        }
        float v = a;
        v = fmaxf(v, __shfl_xor(v, 1));
        v = fmaxf(v, __shfl_xor(v, 2));
        v = fmaxf(v, __shfl_xor(v, 4));
        v = fmaxf(v, __shfl_xor(v, 8));
        float mn = fmaxf(m, v);
        float scale = __expf(m - mn);
        m = mn;
        float p = (el < nchunk) ? __expf(a - mn) : 0.f;
        pbuf[w][el][hq] = p;
        float ps = p;
        ps += __shfl_xor(ps, 1);
        ps += __shfl_xor(ps, 2);
        ps += __shfl_xor(ps, 4);
        ps += __shfl_xor(ps, 8);
        den = den * scale + ps;
        // stage the chunk's hr rows: 4 passes x (4 rows x 16 lanes x 16B)
        #pragma unroll
        for (int pass = 0; pass < 4; pass++) {
            int rj = pass * 4 + (lane >> 4);
            int pj = __shfl(pk, rj);
            int sj = pj & 0x1FFFF, tj = pj >> 17;
            if (rj < nchunk) {
                uint4 hv = *(const uint4*)(hr + ((long)tj * N + sj) * DH + (lane & 15) * 8);
                *(uint4*)&hrb[w][rj][(lane & 15) * 8] = hv;
            }
        }
        o0 *= scale; o1 *= scale;
        asm volatile("s_waitcnt lgkmcnt(0)" ::: "memory");
        for (int j = 0; j < nchunk; j++) {
            float pj = pbuf[w][j][hq];
            unsigned hv = *(const unsigned*)&hrb[w][j][lane * 2];
            o0 = fmaf(pj, bf2f((ushortT)hv), o0);
            o1 = fmaf(pj, bf2f((ushortT)(hv >> 16)), o1);
        }
    }
    float inv = (den > 0.f) ? 1.f / den : 0.f;
    o0 *= inv; o1 *= inv;
    if (bias) { o0 += bias[2 * lane]; o1 += bias[2 * lane + 1]; }
    if constexpr (ADDS) {
        unsigned sv = ((const unsigned*)adds)[(long)d * 64 + lane];
        o0 += bf2f((ushortT)sv);
        o1 += bf2f((ushortT)(sv >> 16));
    }
    if (act) { o0 = lrelu(o0, 0.01f); o1 = lrelu(o1, 0.01f); }
    if constexpr (sizeof(CT) == 2) {
        unsigned pk2 = (unsigned)f2bf(o0) | ((unsigned)f2bf(o1) << 16);
        ((unsigned*)outp)[(long)d * 64 + lane] = pk2;
    } else {
        *(float2*)((float*)outp + (long)d * DH + lane * 2) = make_float2(o0, o1);
    }
}

__global__ __launch_bounds__(256)
void fill_report(float* __restrict__ out, float v, long total)
{
    long i = (long)blockIdx.x * 256 + threadIdx.x;
    if (i < total) out[i] = v;
}

// ---------------------------------------------------------------------------
extern "C" void kernel_launch(void* const* d_in, const int* in_sizes, int n_in,
                              void* d_out, int out_size, void* d_ws, size_t ws_size,
                              hipStream_t stream)
{
    const float* kg      = (const float*)d_in[0];
    const float* ccle    = (const float*)d_in[1];
    const int*   node_id = (const int*)d_in[2];
    const int*   eidx    = (const int*)d_in[3];
    const int*   etype   = (const int*)d_in[4];
    const float* cw1 = (const float*)d_in[5];
    const float* cb1 = (const float*)d_in[6];
    const float* cw2 = (const float*)d_in[7];
    const float* cb2 = (const float*)d_in[8];
    const float* W1  = (const float*)d_in[9];
    const float* q1  = (const float*)d_in[10];
    const float* k1  = (const float*)d_in[11];
    const float* b1  = (const float*)d_in[12];
    const float* W2  = (const float*)d_in[13];
    const float* q2  = (const float*)d_in[14];
    const float* k2  = (const float*)d_in[15];
    const float* b2  = (const float*)d_in[16];
    const float* sw1 = (const float*)d_in[17];
    const float* sb1 = (const float*)d_in[18];
    const float* sw2 = (const float*)d_in[19];
    const float* sb2 = (const float*)d_in[20];

    const int N = in_sizes[2];
    const int E = in_sizes[4];
    const int* src = eidx;
    const int* dst = eidx + E;

    dim3 blk(256);
    long nd = (long)N * 128;
    int nd_blocks = (int)((nd + 255) / 256);
    int eb4 = (E / 4 + 255) / 256;                 // ILP-4 edge kernels

    // ---- workspace layout ----
    const long WTN = (long)9 * BN * 256;           // WT slots (max K=256)
    size_t need = (size_t)N * (256 + 128 + 128 + 1024) * 2 + (size_t)WTN * 2
                + (size_t)N * 64 * 4 + (size_t)N * 128 * 4
                + ((size_t)3 * N + 257 + (size_t)E) * 4;
    if (ws_size < need) {
        fill_report<<<nd_blocks, blk, 0, stream>>>((float*)d_out,
            (float)(double)(ws_size >> 20), nd);
        return;
    }
    ushortT* xb  = (ushortT*)d_ws;                 // 256N
    ushortT* x1b = xb + (long)N * CIN1;            // 128N
    ushortT* s1b = x1b + (long)N * DH;             // 128N
    ushortT* hr  = s1b + (long)N * DH;             // 1024N
    ushortT* WT  = hr + (long)RREL * N * DH;       // WTN
    float* aqk   = (float*)(WT + WTN);             // 64N, layout [r][n][8]
    ushortT* s2b = (ushortT*)(aqk + (long)N * 64); // 128N bf16 (region is 128N f32)
    int* rowptr  = (int*)((float*)s2b + (long)N * DH);  // N+1
    int* cursor  = rowptr + (N + 1);
    int* deg     = cursor + N;
    int* bsum    = deg + N;
    int* ses     = bsum + 256;                     // E packed (et<<17)|src

    int nb = (N + SCAN_BLK - 1) / SCAN_BLK;
    int fgrid = (N + 3) / 4;
    int mblocks = (N + 127) / 128;
    dim3 ggrid(mblocks * 9);

    // encoder -> xb (bf16 [kg | enc]); 64 nodes per block
    encoder_kernel<<<(N + 63) / 64, blk, 0, stream>>>(kg, ccle, node_id,
        cw1, cb1, cw2, cb2, xb, N);

    // CSR build (shared by both layers)
    hipMemsetAsync(deg, 0, (size_t)N * sizeof(int), stream);
    hist_kernel<<<eb4, blk, 0, stream>>>(dst, deg, E);
    scan1_kernel<<<nb, blk, 0, stream>>>(deg, rowptr, bsum, N);
    scan2_kernel<<<1, 64, 0, stream>>>(bsum, nb);
    scan3_kernel<<<(N + 255) / 256, blk, 0, stream>>>(rowptr, bsum, cursor, N, E);
    scatter_kernel<<<eb4, blk, 0, stream>>>(src, dst, etype, cursor, ses, E);

    // ---- layer 1 ----
    wtrans_kernel<<<(int)(((long)9 * BN * CIN1 + 255) / 256), blk, 0, stream>>>(
        W1, q1, k1, sw1, WT, CIN1);
    mfma_gemm<<<ggrid, blk, 0, stream>>>(xb, xb, WT, hr, aqk, sb1, s1b,
        /*actskip=*/1, N, CIN1);
    fused_agg<ushortT, false><<<fgrid, blk, 0, stream>>>(rowptr, ses,
        aqk, hr, b1, nullptr, x1b, N, 1);

    // ---- layer 2 ----
    wtrans_kernel<<<(int)(((long)9 * BN * DH + 255) / 256), blk, 0, stream>>>(
        W2, q2, k2, sw2, WT, DH);
    mfma_gemm<<<ggrid, blk, 0, stream>>>(x1b, s1b, WT, hr, aqk, sb2, s2b,
        /*actskip=*/0, N, DH);
    fused_agg<float, true><<<fgrid, blk, 0, stream>>>(rowptr, ses,
        aqk, hr, b2, s2b, (float*)d_out, N, 1);
}